// Round 6
// baseline (411.585 us; speedup 1.0000x reference)
//
#include <hip/hip_runtime.h>
#include <math.h>

typedef unsigned short u16;
typedef short s16x4 __attribute__((ext_vector_type(4)));
typedef short s16x8 __attribute__((ext_vector_type(8)));
typedef __bf16 bf16x8 __attribute__((ext_vector_type(8)));
typedef float f32x4 __attribute__((ext_vector_type(4)));

#define S_LEN 2048
#define NHEAD 16
#define QCOLS 3072        // NH*192
#define VCOLS 2048        // NH*128
#define ATT_SCALE 0.07216878364870323f   // 1/sqrt(192)

__device__ __forceinline__ u16 f2bf(float f) {
    unsigned u = __float_as_uint(f);
    u += 0x7fffu + ((u >> 16) & 1u);      // RNE
    return (u16)(u >> 16);
}
__device__ __forceinline__ float bf2f(u16 h) {
    return __uint_as_float(((unsigned)h) << 16);
}

// global -> LDS direct (16B/lane). LDS dest is wave-uniform base + lane*16.
typedef const __attribute__((address_space(1))) void gas_void;
typedef __attribute__((address_space(3))) void las_void;
__device__ __forceinline__ void gload_lds16(const void* g, void* l) {
    __builtin_amdgcn_global_load_lds(
        (gas_void*)(unsigned long long)g,
        (las_void*)(unsigned)(unsigned long long)l, 16, 0, 0);
}

// =====================================================================
// bf16 MFMA GEMM, 2-phase prefetch: C = A[M][K] @ Bt[N][K].
// 256 thr = 4 waves (2x2); BK=64; double-buffered LDS.
// OMODE: 0 f32 out | 1 bf16 out | 2 bf16 transposed out | 3 bf16+RoPE
//        4 fused K/V up-proj: N=5120; cols<3072 -> KBUF (+rope on band%3==2),
//          cols>=3072 -> Cv2 transposed (VT[col-3072][M]).
// =====================================================================
template<int BM, int BN, int OMODE>
__global__ __launch_bounds__(256) void gemm_bf16(
    const u16* __restrict__ A, const u16* __restrict__ Bt,
    void* __restrict__ Cv, int M, int N, int K,
    const float* __restrict__ cost, const float* __restrict__ sint,
    u16* __restrict__ Cv2)
{
    constexpr int BK = 64;
    __shared__ u16 As[2][BM * BK];
    __shared__ u16 Bs[2][BN * BK];
    const int t = threadIdx.x;
    const int lane = t & 63, wid = t >> 6;
    const int wr = wid >> 1, wc = wid & 1;
    const int g = lane >> 4, cl = lane & 15;
    const size_t bm = (size_t)blockIdx.y * BM;
    const size_t bn = (size_t)blockIdx.x * BN;
    constexpr int MR = BM / 32, NR = BN / 32;
    constexpr int APW = BM * BK * 2 / 1024 / 4;   // 1KB rounds per wave (A)
    constexpr int BPW = BN * BK * 2 / 1024 / 4;

    auto stage = [&](int buf, int k0) {
#pragma unroll
        for (int i = 0; i < APW; ++i) {
            int rnd = wid * APW + i;
            int fb  = (rnd << 10) + (lane << 4);
            int row = fb >> 7;                    // 128 B per row (BK=64)
            int ke  = (fb & 127) >> 1;
            gload_lds16(A + (bm + row) * K + k0 + ke, (char*)As[buf] + (rnd << 10));
        }
#pragma unroll
        for (int i = 0; i < BPW; ++i) {
            int rnd = wid * BPW + i;
            int fb  = (rnd << 10) + (lane << 4);
            int row = fb >> 7;
            int ke  = (fb & 127) >> 1;
            gload_lds16(Bt + (bn + row) * K + k0 + ke, (char*)Bs[buf] + (rnd << 10));
        }
    };

    f32x4 acc[MR][NR] = {};
    stage(0, 0);
    int cur = 0;
    for (int k0 = 0; k0 < K; k0 += BK) {
        __syncthreads();   // drains vmcnt(0): buf[cur] staged; buf[cur^1] free
        if (k0 + BK < K) stage(cur ^ 1, k0 + BK);   // async, overlaps compute
#pragma unroll
        for (int ks = 0; ks < 2; ++ks) {
            s16x8 av[MR], bv[NR];
#pragma unroll
            for (int m = 0; m < MR; ++m)
                av[m] = *(const s16x8*)((const char*)As[cur] +
                        (wr*(BM/2) + m*16 + cl) * 128 + ks*64 + g*16);
#pragma unroll
            for (int n = 0; n < NR; ++n)
                bv[n] = *(const s16x8*)((const char*)Bs[cur] +
                        (wc*(BN/2) + n*16 + cl) * 128 + ks*64 + g*16);
#pragma unroll
            for (int m = 0; m < MR; ++m)
#pragma unroll
                for (int n = 0; n < NR; ++n)
                    acc[m][n] = __builtin_amdgcn_mfma_f32_16x16x32_bf16(
                        __builtin_bit_cast(bf16x8, av[m]),
                        __builtin_bit_cast(bf16x8, bv[n]), acc[m][n], 0, 0, 0);
        }
        cur ^= 1;
    }

    // epilogue: C layout col=lane&15, row=(lane>>4)*4+j (m89-verified)
    if constexpr (OMODE == 3 || OMODE == 4) {
        const int band = ((int)(bn >> 6)) + wc;       // global 64-col band
        u16* C = (u16*)Cv;
        if (OMODE == 4 && band >= 48) {
            // V region: transposed write VT[col-3072][M]
#pragma unroll
            for (int m = 0; m < MR; ++m)
#pragma unroll
                for (int n = 0; n < NR; ++n) {
                    size_t vcol = bn + wc*(BN/2) + n*16 + cl - 3072;
#pragma unroll
                    for (int j = 0; j < 4; ++j) {
                        size_t row = bm + wr*(BM/2) + m*16 + g*4 + j;
                        Cv2[vcol * M + row] = f2bf(acc[m][n][j]);
                    }
                }
        } else {
            const bool pe = (band % 3) == 2;          // rope band (wave-uniform)
            const int NN = 3072;                      // K output row stride
#pragma unroll
            for (int m = 0; m < MR; ++m) {
                const size_t rbase = bm + wr*(BM/2) + m*16 + g*4;
                if (pe) {
#pragma unroll
                    for (int n = 0; n < 2; ++n) {
                        const int j = n*16 + cl;      // freq index [0,32)
                        const size_t colA = bn + wc*(BN/2) + n*16 + cl;
#pragma unroll
                        for (int jj = 0; jj < 4; ++jj) {
                            const size_t r = rbase + jj;
                            float co = cost[r*32 + j], sn = sint[r*32 + j];
                            float a = acc[m][n][jj], b = acc[m][n+2][jj];
                            C[r*NN + colA]      = f2bf(a*co - b*sn);
                            C[r*NN + colA + 32] = f2bf(b*co + a*sn);
                        }
                    }
                } else {
#pragma unroll
                    for (int n = 0; n < NR; ++n) {
                        const size_t col = bn + wc*(BN/2) + n*16 + cl;
#pragma unroll
                        for (int jj = 0; jj < 4; ++jj)
                            C[(rbase + jj)*NN + col] = f2bf(acc[m][n][jj]);
                    }
                }
            }
        }
    } else {
#pragma unroll
        for (int m = 0; m < MR; ++m)
#pragma unroll
            for (int n = 0; n < NR; ++n) {
                size_t col = bn + wc*(BN/2) + n*16 + cl;
#pragma unroll
                for (int j = 0; j < 4; ++j) {
                    size_t row = bm + wr*(BM/2) + m*16 + g*4 + j;
                    if constexpr (OMODE == 0)
                        ((float*)Cv)[row * N + col] = acc[m][n][j];
                    else if constexpr (OMODE == 1)
                        ((u16*)Cv)[row * N + col] = f2bf(acc[m][n][j]);
                    else
                        ((u16*)Cv)[col * M + row] = f2bf(acc[m][n][j]);
                }
            }
    }
}

// =====================================================================
// Fused weight transpose+cast (5 weights): fp32 [K][N] -> bf16 [N][K].
// =====================================================================
__global__ __launch_bounds__(256) void transpose_cast5(
    const float* __restrict__ w0, u16* __restrict__ o0,
    const float* __restrict__ w1, u16* __restrict__ o1,
    const float* __restrict__ w2, u16* __restrict__ o2,
    const float* __restrict__ w3, u16* __restrict__ o3,
    const float* __restrict__ w4, u16* __restrict__ o4)
{
    const int z = blockIdx.z;
    const float* in; u16* out; int K, N;
    if      (z == 0) { in = w0; out = o0; K = 2048; N = 1536; }
    else if (z == 1) { in = w1; out = o1; K = 2048; N = 512;  }
    else if (z == 2) { in = w2; out = o2; K = 1536; N = 3072; }
    else if (z == 3) { in = w3; out = o3; K = 512;  N = 3072; }
    else             { in = w4; out = o4; K = 512;  N = 2048; }
    const int bn = blockIdx.x * 32, bk = blockIdx.y * 32;
    if (bn >= N || bk >= K) return;

    __shared__ float tile[32][33];
    const int tx = threadIdx.x & 31, ty = threadIdx.x >> 5;
#pragma unroll
    for (int r = 0; r < 32; r += 8)
        tile[ty + r][tx] = in[(size_t)(bk + ty + r) * N + bn + tx];
    __syncthreads();
#pragma unroll
    for (int r = 0; r < 32; r += 8)
        out[(size_t)(bn + ty + r) * K + bk + tx] = f2bf(tile[tx][ty + r]);
}

__global__ __launch_bounds__(256) void transpose_cast(
    const float* __restrict__ in, u16* __restrict__ out, int K, int N)
{
    __shared__ float tile[32][33];
    const int bk = blockIdx.y * 32, bn = blockIdx.x * 32;
    const int tx = threadIdx.x & 31, ty = threadIdx.x >> 5;
#pragma unroll
    for (int r = 0; r < 32; r += 8)
        tile[ty + r][tx] = in[(size_t)(bk + ty + r) * N + bn + tx];
    __syncthreads();
#pragma unroll
    for (int r = 0; r < 32; r += 8)
        out[(size_t)(bn + ty + r) * K + bk + tx] = f2bf(tile[tx][ty + r]);
}

__global__ __launch_bounds__(256) void cast_f32_bf16(
    const float* __restrict__ in, u16* __restrict__ out, long n)
{
    long i = ((long)blockIdx.x * 256 + threadIdx.x) * 4;
    if (i >= n) return;
    f32x4 v = *(const f32x4*)(in + i);
    ushort4 q;
    q.x = f2bf(v[0]); q.y = f2bf(v[1]); q.z = f2bf(v[2]); q.w = f2bf(v[3]);
    *(ushort4*)(out + i) = q;
}

// =====================================================================
// Fused double RMSNorm over bf16 buffers (in place).
// grid 4096: rows [0,2048) -> q latent (N=1536), rows [2048,4096) -> kv (512).
// =====================================================================
__global__ __launch_bounds__(256) void rmsnorm2(
    u16* __restrict__ qb, const float* __restrict__ qw,
    u16* __restrict__ kvb, const float* __restrict__ kvw)
{
    const int r = blockIdx.x;
    u16* buf; const float* w; int N; float invN;
    if (r < 2048) { buf = qb + (size_t)r * 1536; w = qw; N = 1536; invN = 1.f/1536.f; }
    else { buf = kvb + (size_t)(r - 2048) * 512; w = kvw; N = 512; invN = 1.f/512.f; }
    const int t = threadIdx.x;

    float ss = 0.f;
    for (int i = t * 8; i < N; i += 2048) {
        s16x8 v = *(const s16x8*)&buf[i];
#pragma unroll
        for (int e = 0; e < 8; ++e) { float f = bf2f((u16)v[e]); ss += f * f; }
    }
#pragma unroll
    for (int off = 32; off > 0; off >>= 1) ss += __shfl_down(ss, off, 64);
    __shared__ float red[4];
    __shared__ float sinv;
    if ((t & 63) == 0) red[t >> 6] = ss;
    __syncthreads();
    if (t == 0) sinv = rsqrtf((red[0]+red[1]+red[2]+red[3]) * invN + 1e-5f);
    __syncthreads();
    const float si = sinv;
    for (int i = t * 8; i < N; i += 2048) {
        s16x8 v = *(const s16x8*)&buf[i];
        s16x8 o;
#pragma unroll
        for (int e = 0; e < 8; ++e)
            o[e] = (short)f2bf(bf2f((u16)v[e]) * w[i + e] * si);
        *(s16x8*)&buf[i] = o;
    }
}

// RoPE cos/sin table: [S][32]
__global__ __launch_bounds__(256) void rope_table_k(
    float* __restrict__ cost, float* __restrict__ sint)
{
    int idx = blockIdx.x * 256 + threadIdx.x;     // S*32
    int tp = idx >> 5, j = idx & 31;
    float invf = powf(100000.0f, -(float)j * (1.0f / 32.0f));
    float fr = (float)tp * invf;
    cost[idx] = cosf(fr);
    sint[idx] = sinf(fr);
}

// =====================================================================
// Attention: swapped QK^T (P row per lane) + in-reg softmax + MFMA PV +
// T14 async reg-staging of K/V (global->reg early, reg->LDS after barrier).
// grid (32, 16); 4 waves; wave owns 16 q-rows; KV tile 64.
// =====================================================================
__global__ __launch_bounds__(256) void attn_mfma(
    const u16* __restrict__ qg, const u16* __restrict__ kg,
    const u16* __restrict__ vtg, u16* __restrict__ og)
{
    __shared__ u16 Ks[64 * 192];       // 24KB, row 384B, swz (row&7)<<4
    __shared__ u16 VTs[128 * 64];      // 16KB, row 128B, swz (dv&7)<<4
    __shared__ u16 Ps[4][16 * 64];     // 8KB, per-wave, row 128B, swz (q&7)<<4

    const int t = threadIdx.x, lane = t & 63, wid = t >> 6;
    const int g = lane >> 4, cl = lane & 15;
    const int h = blockIdx.y;
    const int bx = blockIdx.x;
    const int qt = (bx & 1) ? (31 - (bx >> 1)) : (bx >> 1);  // causal balance
    const int qbase = qt * 64;
    const int wrow = wid * 16;

    // Q fragments (A/B-frag pattern: row|col=lane&15, k=(lane>>4)*8+j)
    s16x8 qv[6];
    {
        const u16* qrow = qg + (size_t)(qbase + wrow + cl) * QCOLS + h * 192;
#pragma unroll
        for (int s = 0; s < 6; ++s)
            qv[s] = *(const s16x8*)(qrow + s * 32 + g * 8);
    }

    float mreg = -1e30f, lreg = 0.f;   // running max/sum for q = cl
    f32x4 accO[8] = {};                // O[q=g*4+j][dv=nb*16+cl]
    char* pw = (char*)Ps[wid];

    // T14 staging registers
    s16x8 kreg[6], vreg[4];
    const char* kh = (const char*)(kg + (size_t)h * 192);
    const char* vh = (const char*)(vtg + (size_t)(h * 128) * S_LEN);

    auto loadKV = [&](int kt2) {
        const char* ksrc = kh + (size_t)(kt2 * 64) * (QCOLS * 2);
#pragma unroll
        for (int i = 0; i < 6; ++i) {
            int fb = i * 4096 + t * 16;
            int row = fb / 384, cb = fb - row * 384;
            kreg[i] = *(const s16x8*)(ksrc + (size_t)row * (QCOLS * 2) + cb);
        }
        const char* vsrc = vh + (size_t)(kt2 * 64) * 2;
#pragma unroll
        for (int i = 0; i < 4; ++i) {
            int fb = i * 4096 + t * 16;
            int dv = fb >> 7, cb = fb & 127;
            vreg[i] = *(const s16x8*)(vsrc + (size_t)dv * (S_LEN * 2) + cb);
        }
    };
    auto writeKV = [&]() {
#pragma unroll
        for (int i = 0; i < 6; ++i) {
            int fb = i * 4096 + t * 16;
            int row = fb / 384, cb = fb - row * 384;
            *(s16x8*)((char*)Ks + row * 384 + (cb ^ ((row & 7) << 4))) = kreg[i];
        }
#pragma unroll
        for (int i = 0; i < 4; ++i) {
            int fb = i * 4096 + t * 16;
            int dv = fb >> 7, cb = fb & 127;
            *(s16x8*)((char*)VTs + dv * 128 + (cb ^ ((dv & 7) << 4))) = vreg[i];
        }
    };

    loadKV(0);
    writeKV();          // compiler inserts vmcnt waits on reg use
    __syncthreads();

    for (int kt = 0; kt <= qt; ++kt) {
        const int kbase = kt * 64;
        if (kt < qt) loadKV(kt + 1);   // prefetch overlaps whole compute phase

        // ---- QK^T swapped: accS[n] holds S^T: kv=n*16+g*4+j, q=cl ----
        f32x4 accS[4] = {};
        __builtin_amdgcn_s_setprio(1);
#pragma unroll
        for (int n = 0; n < 4; ++n) {
            const int kvrow = n * 16 + cl;
            const char* krow = (const char*)Ks + kvrow * 384;
            const int sw = (kvrow & 7) << 4;
#pragma unroll
            for (int s = 0; s < 6; ++s) {
                s16x8 kv8 = *(const s16x8*)(krow + ((s * 64 + g * 16) ^ sw));
                accS[n] = __builtin_amdgcn_mfma_f32_16x16x32_bf16(
                    __builtin_bit_cast(bf16x8, kv8),
                    __builtin_bit_cast(bf16x8, qv[s]), accS[n], 0, 0, 0);
            }
        }
        __builtin_amdgcn_s_setprio(0);

        // ---- mask + scale + online softmax, all in-register (q = cl) ----
        const int qrow_g = qbase + wrow + cl;
        float pm[4][4];
        float mx = -1e30f;
#pragma unroll
        for (int n = 0; n < 4; ++n)
#pragma unroll
            for (int j = 0; j < 4; ++j) {
                int kcol = kbase + n * 16 + g * 4 + j;
                float s = accS[n][j] * ATT_SCALE;
                s = (kcol <= qrow_g) ? s : -1e30f;
                pm[n][j] = s;
                mx = fmaxf(mx, s);
            }
        mx = fmaxf(mx, __shfl_xor(mx, 16, 64));
        mx = fmaxf(mx, __shfl_xor(mx, 32, 64));
        float mnew = fmaxf(mreg, mx);
        float c = __expf(mreg - mnew);
        float rs = 0.f;
#pragma unroll
        for (int n = 0; n < 4; ++n)
#pragma unroll
            for (int j = 0; j < 4; ++j) {
                float p = __expf(pm[n][j] - mnew);
                pm[n][j] = p;
                rs += p;
            }
        rs += __shfl_xor(rs, 16, 64);
        rs += __shfl_xor(rs, 32, 64);
        lreg = lreg * c + rs;
        mreg = mnew;

        // ---- P write: 4x ds_write_b64 (row q=cl, kv block n*16+g*4) ----
#pragma unroll
        for (int n = 0; n < 4; ++n) {
            s16x4 pk;
#pragma unroll
            for (int j = 0; j < 4; ++j) pk[j] = (short)f2bf(pm[n][j]);
            int byte = (cl * 128 + n * 32 + g * 8) ^ ((cl & 7) << 4);
            *(s16x4*)(pw + byte) = pk;
        }

        // ---- rescale O (c broadcast from lane q=g*4+j) ----
        float cj[4];
#pragma unroll
        for (int j = 0; j < 4; ++j) cj[j] = __shfl(c, g * 4 + j, 64);
#pragma unroll
        for (int nb = 0; nb < 8; ++nb)
#pragma unroll
            for (int j = 0; j < 4; ++j) accO[nb][j] *= cj[j];

        // ---- PV via MFMA ----
        __builtin_amdgcn_s_setprio(1);
#pragma unroll
        for (int ks = 0; ks < 2; ++ks) {
            s16x8 pa = *(const s16x8*)(pw +
                ((cl * 128 + ks * 64 + g * 16) ^ ((cl & 7) << 4)));
#pragma unroll
            for (int nb = 0; nb < 8; ++nb) {
                s16x8 vb = *(const s16x8*)((const char*)VTs +
                    (((nb * 16 + cl) * 128 + ks * 64 + g * 16) ^ ((cl & 7) << 4)));
                accO[nb] = __builtin_amdgcn_mfma_f32_16x16x32_bf16(
                    __builtin_bit_cast(bf16x8, pa),
                    __builtin_bit_cast(bf16x8, vb), accO[nb], 0, 0, 0);
            }
        }
        __builtin_amdgcn_s_setprio(0);

        __syncthreads();             // all waves done reading Ks/VTs; vmcnt drained
        if (kt < qt) writeKV();      // regs -> LDS (fast, no HBM latency)
        __syncthreads();             // writes visible
    }

    // ---- epilogue: O /= l (broadcast from lane q=g*4+j), store bf16 ----
    float li[4];
#pragma unroll
    for (int j = 0; j < 4; ++j) li[j] = 1.f / __shfl(lreg, g * 4 + j, 64);
#pragma unroll
    for (int j = 0; j < 4; ++j) {
        u16* orow = og + (size_t)(qbase + wrow + g * 4 + j) * VCOLS + h * 128;
#pragma unroll
        for (int nb = 0; nb < 8; ++nb)
            orow[nb * 16 + cl] = f2bf(accO[nb][j] * li[j]);
    }
}

// =====================================================================
// Host launcher
// =====================================================================
extern "C" void kernel_launch(void* const* d_in, const int* in_sizes, int n_in,
                              void* d_out, int out_size, void* d_ws, size_t ws_size,
                              hipStream_t stream)
{
    const float* x         = (const float*)d_in[0];
    const float* wq_down   = (const float*)d_in[1];
    const float* q_norm_w  = (const float*)d_in[2];
    const float* wq_up     = (const float*)d_in[3];
    const float* wkv_down  = (const float*)d_in[4];
    const float* kv_norm_w = (const float*)d_in[5];
    const float* wk_up     = (const float*)d_in[6];
    const float* wv_up     = (const float*)d_in[7];
    const float* wo        = (const float*)d_in[8];
    float* out = (float*)d_out;
    char* ws = (char*)d_ws;

    u16*  WQD_T  = (u16*)(ws + 0);            // 6,291,456 B
    u16*  WKVD_T = (u16*)(ws + 6291456);      // 2,097,152
    u16*  WKU_T  = (u16*)(ws + 8388608);      // 3,145,728  (contiguous with
    u16*  WVU_T  = (u16*)(ws + 11534336);     // 2,097,152   WVU_T: fused N=5120)
    u16*  WQU_T  = (u16*)(ws + 13631488);     // 9,437,184
    u16*  XBF    = (u16*)(ws + 23068672);     // 8,388,608
    u16*  VTBUF  = (u16*)(ws + 31457280);     // 8,388,608
    u16*  QLATB  = (u16*)(ws + 48234496);     // 6,291,456 (bf16, in-place norm)
    u16*  KVLATB = (u16*)(ws + 54525952);     // 2,097,152
    u16*  QBUF   = (u16*)(ws + 56623104);     // 12,582,912
    u16*  KBUF   = (u16*)(ws + 69206016);     // 12,582,912
    float* COST  = (float*)(ws + 81788928);   // 262,144
    float* SINT  = (float*)(ws + 82051072);   // 262,144
    // aliases over dead regions:
    u16*  WO_T   = (u16*)(ws + 0);            // over WQD_T+WKVD_T (dead after down-proj)
    u16*  ATTNO  = (u16*)(ws + 23068672);     // over XBF (dead after down-proj)

    // weight prep + x cast + rope table
    transpose_cast5<<<dim3(96, 64, 5), 256, 0, stream>>>(
        wq_down, WQD_T, wkv_down, WKVD_T, wq_up, WQU_T, wk_up, WKU_T, wv_up, WVU_T);
    cast_f32_bf16<<<4096, 256, 0, stream>>>(x, XBF, (long)S_LEN * 2048);
    rope_table_k<<<256, 256, 0, stream>>>(COST, SINT);

    // down-projections (bf16 out, normalized in place next)
    gemm_bf16<128,128,1><<<dim3(12, 16), 256, 0, stream>>>(
        XBF, WQD_T,  QLATB,  2048, 1536, 2048, nullptr, nullptr, nullptr);
    gemm_bf16< 64, 64,1><<<dim3( 8, 32), 256, 0, stream>>>(
        XBF, WKVD_T, KVLATB, 2048,  512, 2048, nullptr, nullptr, nullptr);
    rmsnorm2<<<4096, 256, 0, stream>>>(QLATB, q_norm_w, KVLATB, kv_norm_w);
    transpose_cast<<<dim3(64, 64), 256, 0, stream>>>(wo, WO_T, 2048, 2048);

    // up-projections: q (rope fused); k+v fused in ONE gemm (N=5120)
    gemm_bf16<128,128,3><<<dim3(24, 16), 256, 0, stream>>>(
        QLATB,  WQU_T, QBUF, 2048, 3072, 1536, COST, SINT, nullptr);
    gemm_bf16<128,128,4><<<dim3(40, 16), 256, 0, stream>>>(
        KVLATB, WKU_T, KBUF, 2048, 5120, 512,  COST, SINT, VTBUF);

    // attention + output projection
    attn_mfma<<<dim3(32, 16), 256, 0, stream>>>(QBUF, KBUF, VTBUF, ATTNO);
    gemm_bf16<128,128,0><<<dim3(16, 16), 256, 0, stream>>>(
        ATTNO, WO_T, out, 2048, 2048, 2048, nullptr, nullptr, nullptr);
}

// Round 7
// 353.721 us; speedup vs baseline: 1.1636x; 1.1636x over previous
//
#include <hip/hip_runtime.h>
#include <math.h>

typedef unsigned short u16;
typedef short s16x4 __attribute__((ext_vector_type(4)));
typedef short s16x8 __attribute__((ext_vector_type(8)));
typedef __bf16 bf16x8 __attribute__((ext_vector_type(8)));
typedef float f32x4 __attribute__((ext_vector_type(4)));

#define S_LEN 2048
#define NHEAD 16
#define QCOLS 3072        // NH*192
#define VCOLS 2048        // NH*128
#define ATT_SCALE 0.07216878364870323f   // 1/sqrt(192)

__device__ __forceinline__ u16 f2bf(float f) {
    unsigned u = __float_as_uint(f);
    u += 0x7fffu + ((u >> 16) & 1u);      // RNE
    return (u16)(u >> 16);
}
__device__ __forceinline__ float bf2f(u16 h) {
    return __uint_as_float(((unsigned)h) << 16);
}

// global -> LDS direct (16B/lane). LDS dest is wave-uniform base + lane*16.
typedef const __attribute__((address_space(1))) void gas_void;
typedef __attribute__((address_space(3))) void las_void;
__device__ __forceinline__ void gload_lds16(const void* g, void* l) {
    __builtin_amdgcn_global_load_lds(
        (gas_void*)(unsigned long long)g,
        (las_void*)(unsigned)(unsigned long long)l, 16, 0, 0);
}

// =====================================================================
// bf16 MFMA GEMM, 2-phase prefetch: C = A[M][K] @ Bt[N][K].
// 256 thr = 4 waves (2x2); BK=64; double-buffered LDS.
// OMODE: 0 f32 out | 1 bf16 out | 2 bf16 transposed out | 3 bf16+RoPE
//        4 fused K/V up-proj: N=5120; cols<3072 -> KBUF (+rope on band%3==2),
//          cols>=3072 -> Cv2 transposed (VT[col-3072][M]).
// =====================================================================
template<int BM, int BN, int OMODE>
__global__ __launch_bounds__(256) void gemm_bf16(
    const u16* __restrict__ A, const u16* __restrict__ Bt,
    void* __restrict__ Cv, int M, int N, int K,
    const float* __restrict__ cost, const float* __restrict__ sint,
    u16* __restrict__ Cv2)
{
    constexpr int BK = 64;
    __shared__ u16 As[2][BM * BK];
    __shared__ u16 Bs[2][BN * BK];
    const int t = threadIdx.x;
    const int lane = t & 63, wid = t >> 6;
    const int wr = wid >> 1, wc = wid & 1;
    const int g = lane >> 4, cl = lane & 15;
    const size_t bm = (size_t)blockIdx.y * BM;
    const size_t bn = (size_t)blockIdx.x * BN;
    constexpr int MR = BM / 32, NR = BN / 32;
    constexpr int APW = BM * BK * 2 / 1024 / 4;   // 1KB rounds per wave (A)
    constexpr int BPW = BN * BK * 2 / 1024 / 4;

    auto stage = [&](int buf, int k0) {
#pragma unroll
        for (int i = 0; i < APW; ++i) {
            int rnd = wid * APW + i;
            int fb  = (rnd << 10) + (lane << 4);
            int row = fb >> 7;                    // 128 B per row (BK=64)
            int ke  = (fb & 127) >> 1;
            gload_lds16(A + (bm + row) * K + k0 + ke, (char*)As[buf] + (rnd << 10));
        }
#pragma unroll
        for (int i = 0; i < BPW; ++i) {
            int rnd = wid * BPW + i;
            int fb  = (rnd << 10) + (lane << 4);
            int row = fb >> 7;
            int ke  = (fb & 127) >> 1;
            gload_lds16(Bt + (bn + row) * K + k0 + ke, (char*)Bs[buf] + (rnd << 10));
        }
    };

    f32x4 acc[MR][NR] = {};
    stage(0, 0);
    int cur = 0;
    for (int k0 = 0; k0 < K; k0 += BK) {
        __syncthreads();   // drains vmcnt(0): buf[cur] staged; buf[cur^1] free
        if (k0 + BK < K) stage(cur ^ 1, k0 + BK);   // async, overlaps compute
#pragma unroll
        for (int ks = 0; ks < 2; ++ks) {
            s16x8 av[MR], bv[NR];
#pragma unroll
            for (int m = 0; m < MR; ++m)
                av[m] = *(const s16x8*)((const char*)As[cur] +
                        (wr*(BM/2) + m*16 + cl) * 128 + ks*64 + g*16);
#pragma unroll
            for (int n = 0; n < NR; ++n)
                bv[n] = *(const s16x8*)((const char*)Bs[cur] +
                        (wc*(BN/2) + n*16 + cl) * 128 + ks*64 + g*16);
#pragma unroll
            for (int m = 0; m < MR; ++m)
#pragma unroll
                for (int n = 0; n < NR; ++n)
                    acc[m][n] = __builtin_amdgcn_mfma_f32_16x16x32_bf16(
                        __builtin_bit_cast(bf16x8, av[m]),
                        __builtin_bit_cast(bf16x8, bv[n]), acc[m][n], 0, 0, 0);
        }
        cur ^= 1;
    }

    // epilogue: C layout col=lane&15, row=(lane>>4)*4+j (m89-verified)
    if constexpr (OMODE == 3 || OMODE == 4) {
        const int band = ((int)(bn >> 6)) + wc;       // global 64-col band
        u16* C = (u16*)Cv;
        if (OMODE == 4 && band >= 48) {
            // V region: transposed write VT[col-3072][M]
#pragma unroll
            for (int m = 0; m < MR; ++m)
#pragma unroll
                for (int n = 0; n < NR; ++n) {
                    size_t vcol = bn + wc*(BN/2) + n*16 + cl - 3072;
#pragma unroll
                    for (int j = 0; j < 4; ++j) {
                        size_t row = bm + wr*(BM/2) + m*16 + g*4 + j;
                        Cv2[vcol * M + row] = f2bf(acc[m][n][j]);
                    }
                }
        } else {
            const bool pe = (band % 3) == 2;          // rope band (wave-uniform)
            const int NN = 3072;                      // K output row stride
#pragma unroll
            for (int m = 0; m < MR; ++m) {
                const size_t rbase = bm + wr*(BM/2) + m*16 + g*4;
                if (pe) {
#pragma unroll
                    for (int n = 0; n < 2; ++n) {
                        const int j = n*16 + cl;      // freq index [0,32)
                        const size_t colA = bn + wc*(BN/2) + n*16 + cl;
#pragma unroll
                        for (int jj = 0; jj < 4; ++jj) {
                            const size_t r = rbase + jj;
                            float co = cost[r*32 + j], sn = sint[r*32 + j];
                            float a = acc[m][n][jj], b = acc[m][n+2][jj];
                            C[r*NN + colA]      = f2bf(a*co - b*sn);
                            C[r*NN + colA + 32] = f2bf(b*co + a*sn);
                        }
                    }
                } else {
#pragma unroll
                    for (int n = 0; n < NR; ++n) {
                        const size_t col = bn + wc*(BN/2) + n*16 + cl;
#pragma unroll
                        for (int jj = 0; jj < 4; ++jj)
                            C[(rbase + jj)*NN + col] = f2bf(acc[m][n][jj]);
                    }
                }
            }
        }
    } else {
#pragma unroll
        for (int m = 0; m < MR; ++m)
#pragma unroll
            for (int n = 0; n < NR; ++n) {
                size_t col = bn + wc*(BN/2) + n*16 + cl;
#pragma unroll
                for (int j = 0; j < 4; ++j) {
                    size_t row = bm + wr*(BM/2) + m*16 + g*4 + j;
                    if constexpr (OMODE == 0)
                        ((float*)Cv)[row * N + col] = acc[m][n][j];
                    else if constexpr (OMODE == 1)
                        ((u16*)Cv)[row * N + col] = f2bf(acc[m][n][j]);
                    else
                        ((u16*)Cv)[col * M + row] = f2bf(acc[m][n][j]);
                }
            }
    }
}

// =====================================================================
// Fused weight transpose+cast (5 weights): fp32 [K][N] -> bf16 [N][K].
// =====================================================================
__global__ __launch_bounds__(256) void transpose_cast5(
    const float* __restrict__ w0, u16* __restrict__ o0,
    const float* __restrict__ w1, u16* __restrict__ o1,
    const float* __restrict__ w2, u16* __restrict__ o2,
    const float* __restrict__ w3, u16* __restrict__ o3,
    const float* __restrict__ w4, u16* __restrict__ o4)
{
    const int z = blockIdx.z;
    const float* in; u16* out; int K, N;
    if      (z == 0) { in = w0; out = o0; K = 2048; N = 1536; }
    else if (z == 1) { in = w1; out = o1; K = 2048; N = 512;  }
    else if (z == 2) { in = w2; out = o2; K = 1536; N = 3072; }
    else if (z == 3) { in = w3; out = o3; K = 512;  N = 3072; }
    else             { in = w4; out = o4; K = 512;  N = 2048; }
    const int bn = blockIdx.x * 32, bk = blockIdx.y * 32;
    if (bn >= N || bk >= K) return;

    __shared__ float tile[32][33];
    const int tx = threadIdx.x & 31, ty = threadIdx.x >> 5;
#pragma unroll
    for (int r = 0; r < 32; r += 8)
        tile[ty + r][tx] = in[(size_t)(bk + ty + r) * N + bn + tx];
    __syncthreads();
#pragma unroll
    for (int r = 0; r < 32; r += 8)
        out[(size_t)(bn + ty + r) * K + bk + tx] = f2bf(tile[tx][ty + r]);
}

__global__ __launch_bounds__(256) void transpose_cast(
    const float* __restrict__ in, u16* __restrict__ out, int K, int N)
{
    __shared__ float tile[32][33];
    const int bk = blockIdx.y * 32, bn = blockIdx.x * 32;
    const int tx = threadIdx.x & 31, ty = threadIdx.x >> 5;
#pragma unroll
    for (int r = 0; r < 32; r += 8)
        tile[ty + r][tx] = in[(size_t)(bk + ty + r) * N + bn + tx];
    __syncthreads();
#pragma unroll
    for (int r = 0; r < 32; r += 8)
        out[(size_t)(bn + ty + r) * K + bk + tx] = f2bf(tile[tx][ty + r]);
}

__global__ __launch_bounds__(256) void cast_f32_bf16(
    const float* __restrict__ in, u16* __restrict__ out, long n)
{
    long i = ((long)blockIdx.x * 256 + threadIdx.x) * 4;
    if (i >= n) return;
    f32x4 v = *(const f32x4*)(in + i);
    ushort4 q;
    q.x = f2bf(v[0]); q.y = f2bf(v[1]); q.z = f2bf(v[2]); q.w = f2bf(v[3]);
    *(ushort4*)(out + i) = q;
}

// =====================================================================
// Fused double RMSNorm over bf16 buffers (in place).
// =====================================================================
__global__ __launch_bounds__(256) void rmsnorm2(
    u16* __restrict__ qb, const float* __restrict__ qw,
    u16* __restrict__ kvb, const float* __restrict__ kvw)
{
    const int r = blockIdx.x;
    u16* buf; const float* w; int N; float invN;
    if (r < 2048) { buf = qb + (size_t)r * 1536; w = qw; N = 1536; invN = 1.f/1536.f; }
    else { buf = kvb + (size_t)(r - 2048) * 512; w = kvw; N = 512; invN = 1.f/512.f; }
    const int t = threadIdx.x;

    float ss = 0.f;
    for (int i = t * 8; i < N; i += 2048) {
        s16x8 v = *(const s16x8*)&buf[i];
#pragma unroll
        for (int e = 0; e < 8; ++e) { float f = bf2f((u16)v[e]); ss += f * f; }
    }
#pragma unroll
    for (int off = 32; off > 0; off >>= 1) ss += __shfl_down(ss, off, 64);
    __shared__ float red[4];
    __shared__ float sinv;
    if ((t & 63) == 0) red[t >> 6] = ss;
    __syncthreads();
    if (t == 0) sinv = rsqrtf((red[0]+red[1]+red[2]+red[3]) * invN + 1e-5f);
    __syncthreads();
    const float si = sinv;
    for (int i = t * 8; i < N; i += 2048) {
        s16x8 v = *(const s16x8*)&buf[i];
        s16x8 o;
#pragma unroll
        for (int e = 0; e < 8; ++e)
            o[e] = (short)f2bf(bf2f((u16)v[e]) * w[i + e] * si);
        *(s16x8*)&buf[i] = o;
    }
}

// RoPE cos/sin table: [S][32]
__global__ __launch_bounds__(256) void rope_table_k(
    float* __restrict__ cost, float* __restrict__ sint)
{
    int idx = blockIdx.x * 256 + threadIdx.x;     // S*32
    int tp = idx >> 5, j = idx & 31;
    float invf = powf(100000.0f, -(float)j * (1.0f / 32.0f));
    float fr = (float)tp * invf;
    cost[idx] = cosf(fr);
    sint[idx] = sinf(fr);
}

// =====================================================================
// Attention: swapped QK^T + in-reg softmax + MFMA PV.
// Staging via gload_lds (pre-swizzled src); K double-buffered in LDS;
// counted vmcnt (T4): V waits vmcnt(6) mid-tile, K(kt+1) drains at tile end.
// grid (32, 16); 4 waves; wave owns 16 q-rows; KV tile 64. LDS 72KB.
// =====================================================================
__global__ __launch_bounds__(256) void attn_mfma(
    const u16* __restrict__ qg, const u16* __restrict__ kg,
    const u16* __restrict__ vtg, u16* __restrict__ og)
{
    __shared__ u16 Ks[2][64 * 192];    // 2x24KB, row 384B, swz (row&7)<<4
    __shared__ u16 VTs[128 * 64];      // 16KB, row 128B, swz (dv&7)<<4
    __shared__ u16 Ps[4][16 * 64];     // 8KB, per-wave, row 128B, swz (q&7)<<4

    const int t = threadIdx.x, lane = t & 63, wid = t >> 6;
    const int g = lane >> 4, cl = lane & 15;
    const int h = blockIdx.y;
    const int bx = blockIdx.x;
    const int qt = (bx & 1) ? (31 - (bx >> 1)) : (bx >> 1);  // causal balance
    const int qbase = qt * 64;
    const int wrow = wid * 16;

    // Q fragments (A/B-frag pattern: row|col=lane&15, k=(lane>>4)*8+j)
    s16x8 qv[6];
    {
        const u16* qrow = qg + (size_t)(qbase + wrow + cl) * QCOLS + h * 192;
#pragma unroll
        for (int s = 0; s < 6; ++s)
            qv[s] = *(const s16x8*)(qrow + s * 32 + g * 8);
    }

    float mreg = -1e30f, lreg = 0.f;   // running max/sum for q = cl
    f32x4 accO[8] = {};                // O[q=g*4+j][dv=nb*16+cl]
    char* pw = (char*)Ps[wid];

    const char* kh = (const char*)(kg + (size_t)h * 192);
    const char* vh = (const char*)(vtg + (size_t)(h * 128) * S_LEN);

    auto stageK = [&](int kt2, int buf) {
        const char* ksrc = kh + (size_t)(kt2 * 64) * (QCOLS * 2);
#pragma unroll
        for (int i = 0; i < 6; ++i) {
            int rnd = wid * 6 + i;
            int fb  = (rnd << 10) + (lane << 4);
            int row = fb / 384;
            int cb  = fb - row * 384;
            gload_lds16(ksrc + (size_t)row * (QCOLS * 2) + (cb ^ ((row & 7) << 4)),
                        (char*)Ks + buf * 24576 + (rnd << 10));
        }
    };
    auto stageV = [&](int kt2) {
        const char* vsrc = vh + (size_t)(kt2 * 64) * 2;
#pragma unroll
        for (int i = 0; i < 4; ++i) {
            int rnd = wid * 4 + i;
            int fb  = (rnd << 10) + (lane << 4);
            int dv  = fb >> 7;
            int cb  = fb & 127;
            gload_lds16(vsrc + (size_t)dv * (S_LEN * 2) + (cb ^ ((dv & 7) << 4)),
                        (char*)VTs + (rnd << 10));
        }
    };

    // prologue: K(0) resident before loop
    stageK(0, 0);
    asm volatile("s_waitcnt vmcnt(0)" ::: "memory");
    __builtin_amdgcn_s_barrier();

    int cur = 0;
    for (int kt = 0; kt <= qt; ++kt) {
        const int kbase = kt * 64;
        // issue this tile's V and next tile's K; never drain mid-loop
        stageV(kt);                               // 4 gloads -> VTs
        if (kt < qt) stageK(kt + 1, cur ^ 1);     // 6 gloads -> Ks[cur^1]

        // ---- QK^T swapped (from resident Ks[cur]): kv=n*16+g*4+j, q=cl ----
        f32x4 accS[4] = {};
        const char* kbuf = (const char*)Ks + cur * 24576;
        __builtin_amdgcn_s_setprio(1);
#pragma unroll
        for (int n = 0; n < 4; ++n) {
            const int kvrow = n * 16 + cl;
            const char* krow = kbuf + kvrow * 384;
            const int sw = (kvrow & 7) << 4;
#pragma unroll
            for (int s = 0; s < 6; ++s) {
                s16x8 kv8 = *(const s16x8*)(krow + ((s * 64 + g * 16) ^ sw));
                accS[n] = __builtin_amdgcn_mfma_f32_16x16x32_bf16(
                    __builtin_bit_cast(bf16x8, kv8),
                    __builtin_bit_cast(bf16x8, qv[s]), accS[n], 0, 0, 0);
            }
        }
        __builtin_amdgcn_s_setprio(0);

        // ---- mask + scale + online softmax, in-register (q = cl) ----
        const int qrow_g = qbase + wrow + cl;
        float pm[4][4];
        float mx = -1e30f;
#pragma unroll
        for (int n = 0; n < 4; ++n)
#pragma unroll
            for (int j = 0; j < 4; ++j) {
                int kcol = kbase + n * 16 + g * 4 + j;
                float s = accS[n][j] * ATT_SCALE;
                s = (kcol <= qrow_g) ? s : -1e30f;
                pm[n][j] = s;
                mx = fmaxf(mx, s);
            }
        mx = fmaxf(mx, __shfl_xor(mx, 16, 64));
        mx = fmaxf(mx, __shfl_xor(mx, 32, 64));
        float mnew = fmaxf(mreg, mx);
        float c = __expf(mreg - mnew);
        float rs = 0.f;
#pragma unroll
        for (int n = 0; n < 4; ++n)
#pragma unroll
            for (int j = 0; j < 4; ++j) {
                float p = __expf(pm[n][j] - mnew);
                pm[n][j] = p;
                rs += p;
            }
        rs += __shfl_xor(rs, 16, 64);
        rs += __shfl_xor(rs, 32, 64);
        lreg = lreg * c + rs;
        mreg = mnew;

        // ---- P write: 4x ds_write_b64 (row q=cl) ----
#pragma unroll
        for (int n = 0; n < 4; ++n) {
            s16x4 pk;
#pragma unroll
            for (int j = 0; j < 4; ++j) pk[j] = (short)f2bf(pm[n][j]);
            int byte = (cl * 128 + n * 32 + g * 8) ^ ((cl & 7) << 4);
            *(s16x4*)(pw + byte) = pk;
        }

        // ---- B1: V landed for all waves; K(kt+1) stays in flight ----
        if (kt < qt) { asm volatile("s_waitcnt vmcnt(6)" ::: "memory"); }
        else         { asm volatile("s_waitcnt vmcnt(0)" ::: "memory"); }
        __builtin_amdgcn_sched_barrier(0);
        __builtin_amdgcn_s_barrier();

        // ---- rescale O (c broadcast from lane q=g*4+j) ----
        float cj[4];
#pragma unroll
        for (int j = 0; j < 4; ++j) cj[j] = __shfl(c, g * 4 + j, 64);
#pragma unroll
        for (int nb = 0; nb < 8; ++nb)
#pragma unroll
            for (int j = 0; j < 4; ++j) accO[nb][j] *= cj[j];

        // ---- PV via MFMA ----
        __builtin_amdgcn_s_setprio(1);
#pragma unroll
        for (int ks = 0; ks < 2; ++ks) {
            s16x8 pa = *(const s16x8*)(pw +
                ((cl * 128 + ks * 64 + g * 16) ^ ((cl & 7) << 4)));
#pragma unroll
            for (int nb = 0; nb < 8; ++nb) {
                s16x8 vb = *(const s16x8*)((const char*)VTs +
                    (((nb * 16 + cl) * 128 + ks * 64 + g * 16) ^ ((cl & 7) << 4)));
                accO[nb] = __builtin_amdgcn_mfma_f32_16x16x32_bf16(
                    __builtin_bit_cast(bf16x8, pa),
                    __builtin_bit_cast(bf16x8, vb), accO[nb], 0, 0, 0);
            }
        }
        __builtin_amdgcn_s_setprio(0);

        // ---- B0: K(kt+1) landed; all waves done with VTs ----
        asm volatile("s_waitcnt vmcnt(0)" ::: "memory");
        __builtin_amdgcn_sched_barrier(0);
        __builtin_amdgcn_s_barrier();
        cur ^= 1;
    }

    // ---- epilogue: O /= l (broadcast from lane q=g*4+j), store bf16 ----
    float li[4];
#pragma unroll
    for (int j = 0; j < 4; ++j) li[j] = 1.f / __shfl(lreg, g * 4 + j, 64);
#pragma unroll
    for (int j = 0; j < 4; ++j) {
        u16* orow = og + (size_t)(qbase + wrow + g * 4 + j) * VCOLS + h * 128;
#pragma unroll
        for (int nb = 0; nb < 8; ++nb)
            orow[nb * 16 + cl] = f2bf(accO[nb][j] * li[j]);
    }
}

// =====================================================================
// Host launcher
// =====================================================================
extern "C" void kernel_launch(void* const* d_in, const int* in_sizes, int n_in,
                              void* d_out, int out_size, void* d_ws, size_t ws_size,
                              hipStream_t stream)
{
    const float* x         = (const float*)d_in[0];
    const float* wq_down   = (const float*)d_in[1];
    const float* q_norm_w  = (const float*)d_in[2];
    const float* wq_up     = (const float*)d_in[3];
    const float* wkv_down  = (const float*)d_in[4];
    const float* kv_norm_w = (const float*)d_in[5];
    const float* wk_up     = (const float*)d_in[6];
    const float* wv_up     = (const float*)d_in[7];
    const float* wo        = (const float*)d_in[8];
    float* out = (float*)d_out;
    char* ws = (char*)d_ws;

    u16*  WQD_T  = (u16*)(ws + 0);            // 6,291,456 B
    u16*  WKVD_T = (u16*)(ws + 6291456);      // 2,097,152
    u16*  WKU_T  = (u16*)(ws + 8388608);      // 3,145,728  (contiguous with
    u16*  WVU_T  = (u16*)(ws + 11534336);     // 2,097,152   WVU_T: fused N=5120)
    u16*  WQU_T  = (u16*)(ws + 13631488);     // 9,437,184
    u16*  XBF    = (u16*)(ws + 23068672);     // 8,388,608
    u16*  VTBUF  = (u16*)(ws + 31457280);     // 8,388,608
    u16*  QLATB  = (u16*)(ws + 48234496);     // 6,291,456 (bf16, in-place norm)
    u16*  KVLATB = (u16*)(ws + 54525952);     // 2,097,152
    u16*  QBUF   = (u16*)(ws + 56623104);     // 12,582,912
    u16*  KBUF   = (u16*)(ws + 69206016);     // 12,582,912
    float* COST  = (float*)(ws + 81788928);   // 262,144
    float* SINT  = (float*)(ws + 82051072);   // 262,144
    // aliases over dead regions:
    u16*  WO_T   = (u16*)(ws + 0);            // over WQD_T+WKVD_T (dead after down-proj)
    u16*  ATTNO  = (u16*)(ws + 23068672);     // over XBF (dead after down-proj)

    // weight prep + x cast + rope table
    transpose_cast5<<<dim3(96, 64, 5), 256, 0, stream>>>(
        wq_down, WQD_T, wkv_down, WKVD_T, wq_up, WQU_T, wk_up, WKU_T, wv_up, WVU_T);
    cast_f32_bf16<<<4096, 256, 0, stream>>>(x, XBF, (long)S_LEN * 2048);
    rope_table_k<<<256, 256, 0, stream>>>(COST, SINT);

    // down-projections (bf16 out, normalized in place next)
    gemm_bf16<128,128,1><<<dim3(12, 16), 256, 0, stream>>>(
        XBF, WQD_T,  QLATB,  2048, 1536, 2048, nullptr, nullptr, nullptr);
    gemm_bf16< 64, 64,1><<<dim3( 8, 32), 256, 0, stream>>>(
        XBF, WKVD_T, KVLATB, 2048,  512, 2048, nullptr, nullptr, nullptr);
    rmsnorm2<<<4096, 256, 0, stream>>>(QLATB, q_norm_w, KVLATB, kv_norm_w);
    transpose_cast<<<dim3(64, 64), 256, 0, stream>>>(wo, WO_T, 2048, 2048);

    // up-projections: q (rope fused); k+v fused in ONE gemm (N=5120)
    gemm_bf16<128,128,3><<<dim3(24, 16), 256, 0, stream>>>(
        QLATB,  WQU_T, QBUF, 2048, 3072, 1536, COST, SINT, nullptr);
    gemm_bf16<128,128,4><<<dim3(40, 16), 256, 0, stream>>>(
        KVLATB, WKU_T, KBUF, 2048, 5120, 512,  COST, SINT, VTBUF);

    // attention + output projection
    attn_mfma<<<dim3(32, 16), 256, 0, stream>>>(QBUF, KBUF, VTBUF, ATTNO);
    gemm_bf16<128,128,0><<<dim3(16, 16), 256, 0, stream>>>(
        ATTNO, WO_T, out, 2048, 2048, 2048, nullptr, nullptr, nullptr);
}

// Round 9
// 323.161 us; speedup vs baseline: 1.2736x; 1.0946x over previous
//
#include <hip/hip_runtime.h>
#include <math.h>

typedef unsigned short u16;
typedef short s16x4 __attribute__((ext_vector_type(4)));
typedef short s16x8 __attribute__((ext_vector_type(8)));
typedef __bf16 bf16x8 __attribute__((ext_vector_type(8)));
typedef float f32x4 __attribute__((ext_vector_type(4)));

#define S_LEN 2048
#define NHEAD 16
#define QCOLS 3072        // NH*192
#define VCOLS 2048        // NH*128
#define ATT_SCALE 0.07216878364870323f   // 1/sqrt(192)

__device__ __forceinline__ u16 f2bf(float f) {
    unsigned u = __float_as_uint(f);
    u += 0x7fffu + ((u >> 16) & 1u);      // RNE
    return (u16)(u >> 16);
}
__device__ __forceinline__ float bf2f(u16 h) {
    return __uint_as_float(((unsigned)h) << 16);
}

// global -> LDS direct (16B/lane). LDS dest is wave-uniform base + lane*16.
typedef const __attribute__((address_space(1))) void gas_void;
typedef __attribute__((address_space(3))) void las_void;
__device__ __forceinline__ void gload_lds16(const void* g, void* l) {
    __builtin_amdgcn_global_load_lds(
        (gas_void*)(unsigned long long)g,
        (las_void*)(unsigned)(unsigned long long)l, 16, 0, 0);
}

// =====================================================================
// bf16 MFMA GEMM, 4-deep counted-vmcnt pipeline (T3+T4):
// C = A[M][K] @ Bt[N][K]. 256 thr = 4 waves (2x2); BK=32; 4 LDS buffers;
// raw s_barrier + asm vmcnt (NEVER __syncthreads in the loop — it drains).
// OMODE: 0 f32 out | 1 bf16 out | 2 bf16 transposed | 3 bf16+RoPE (N=3072)
//        4 fused K/V up-proj (N=5120: K cols<3072 + rope, V cols>=3072 -> Cv2^T)
//        5 fused down-proj (N=2048: col<1536 -> Cv stride 1536, else Cv2 stride 512)
// =====================================================================
template<int BM, int BN, int OMODE>
__global__ __launch_bounds__(256) void gemm_bf16(
    const u16* __restrict__ A, const u16* __restrict__ Bt,
    void* __restrict__ Cv, int M, int N, int K,
    const float* __restrict__ cost, const float* __restrict__ sint,
    u16* __restrict__ Cv2)
{
    constexpr int BK = 32;
    __shared__ u16 As[4][BM * BK];
    __shared__ u16 Bs[4][BN * BK];
    const int t = threadIdx.x;
    const int lane = t & 63, wid = t >> 6;
    const int wr = wid >> 1, wc = wid & 1;
    const int g = lane >> 4, cl = lane & 15;
    const size_t bm = (size_t)blockIdx.y * BM;
    const size_t bn = (size_t)blockIdx.x * BN;
    constexpr int MR = BM / 32, NR = BN / 32;
    constexpr int APW = BM * BK * 2 / 1024 / 4;   // 1KB rounds per wave
    constexpr int BPW = BN * BK * 2 / 1024 / 4;
    static_assert(APW + BPW == 4, "LPW must be 4 (vmcnt literals 8/4/0)");

    auto stage = [&](int s, int ti) {
        const int k0 = ti * BK;
#pragma unroll
        for (int i = 0; i < APW; ++i) {
            int rnd = wid * APW + i;
            int fb  = (rnd << 10) + (lane << 4);
            int row = fb >> 6;                    // 64 B per row (BK=32)
            int ke  = (fb & 63) >> 1;
            gload_lds16(A + (bm + row) * K + k0 + ke, (char*)As[s] + (rnd << 10));
        }
#pragma unroll
        for (int i = 0; i < BPW; ++i) {
            int rnd = wid * BPW + i;
            int fb  = (rnd << 10) + (lane << 4);
            int row = fb >> 6;
            int ke  = (fb & 63) >> 1;
            gload_lds16(Bt + (bn + row) * K + k0 + ke, (char*)Bs[s] + (rnd << 10));
        }
    };

    f32x4 acc[MR][NR] = {};
    auto compute = [&](int s) {
        s16x8 av[MR], bv[NR];
#pragma unroll
        for (int m = 0; m < MR; ++m)
            av[m] = *(const s16x8*)((const char*)As[s] +
                    (wr*(BM/2) + m*16 + cl) * 64 + g*16);
#pragma unroll
        for (int n = 0; n < NR; ++n)
            bv[n] = *(const s16x8*)((const char*)Bs[s] +
                    (wc*(BN/2) + n*16 + cl) * 64 + g*16);
        __builtin_amdgcn_s_setprio(1);
#pragma unroll
        for (int m = 0; m < MR; ++m)
#pragma unroll
            for (int n = 0; n < NR; ++n)
                acc[m][n] = __builtin_amdgcn_mfma_f32_16x16x32_bf16(
                    __builtin_bit_cast(bf16x8, av[m]),
                    __builtin_bit_cast(bf16x8, bv[n]), acc[m][n], 0, 0, 0);
        __builtin_amdgcn_s_setprio(0);
    };

    const int nt = K / BK;                 // >= 16 for all our K
    stage(0, 0); stage(1, 1); stage(2, 2);
    for (int ti = 0; ti < nt - 2; ++ti) {
        asm volatile("s_waitcnt vmcnt(8)" ::: "memory");   // stage ti landed
        __builtin_amdgcn_sched_barrier(0);
        __builtin_amdgcn_s_barrier();       // all waves done with slot (ti+3)&3
        if (ti + 3 < nt) stage((ti + 3) & 3, ti + 3);
        compute(ti & 3);
    }
    asm volatile("s_waitcnt vmcnt(4)" ::: "memory");
    __builtin_amdgcn_sched_barrier(0);
    __builtin_amdgcn_s_barrier();
    compute((nt - 2) & 3);
    asm volatile("s_waitcnt vmcnt(0)" ::: "memory");
    __builtin_amdgcn_sched_barrier(0);
    __builtin_amdgcn_s_barrier();
    compute((nt - 1) & 3);

    // epilogue: C layout col=lane&15, row=(lane>>4)*4+j (m89-verified)
    if constexpr (OMODE == 3 || OMODE == 4) {
        const int band = ((int)(bn >> 6)) + wc;       // global 64-col band
        u16* C = (u16*)Cv;
        if (OMODE == 4 && band >= 48) {
            // V region: transposed write VT[col-3072][M]
#pragma unroll
            for (int m = 0; m < MR; ++m)
#pragma unroll
                for (int n = 0; n < NR; ++n) {
                    size_t vcol = bn + wc*(BN/2) + n*16 + cl - 3072;
#pragma unroll
                    for (int j = 0; j < 4; ++j) {
                        size_t row = bm + wr*(BM/2) + m*16 + g*4 + j;
                        Cv2[vcol * M + row] = f2bf(acc[m][n][j]);
                    }
                }
        } else {
            const bool pe = (band % 3) == 2;          // rope band (wave-uniform)
            const int NN = 3072;                      // K output row stride
#pragma unroll
            for (int m = 0; m < MR; ++m) {
                const size_t rbase = bm + wr*(BM/2) + m*16 + g*4;
                if (pe) {
#pragma unroll
                    for (int n = 0; n < 2; ++n) {
                        const int j = n*16 + cl;      // freq index [0,32)
                        const size_t colA = bn + wc*(BN/2) + n*16 + cl;
#pragma unroll
                        for (int jj = 0; jj < 4; ++jj) {
                            const size_t r = rbase + jj;
                            float co = cost[r*32 + j], sn = sint[r*32 + j];
                            float a = acc[m][n][jj], b = acc[m][n+2][jj];
                            C[r*NN + colA]      = f2bf(a*co - b*sn);
                            C[r*NN + colA + 32] = f2bf(b*co + a*sn);
                        }
                    }
                } else {
#pragma unroll
                    for (int n = 0; n < NR; ++n) {
                        const size_t col = bn + wc*(BN/2) + n*16 + cl;
#pragma unroll
                        for (int jj = 0; jj < 4; ++jj)
                            C[(rbase + jj)*NN + col] = f2bf(acc[m][n][jj]);
                    }
                }
            }
        }
    } else if constexpr (OMODE == 5) {
        // fused down-proj: col<1536 -> Cv (stride 1536), else Cv2 (stride 512)
        const bool isq = (bn < 1536);                 // block-uniform (BN=128)
        u16* base = isq ? (u16*)Cv : Cv2;
        const size_t stride = isq ? 1536 : 512;
        const size_t cof = isq ? 0 : 1536;
#pragma unroll
        for (int m = 0; m < MR; ++m)
#pragma unroll
            for (int n = 0; n < NR; ++n) {
                size_t col = bn + wc*(BN/2) + n*16 + cl - cof;
#pragma unroll
                for (int j = 0; j < 4; ++j) {
                    size_t row = bm + wr*(BM/2) + m*16 + g*4 + j;
                    base[row * stride + col] = f2bf(acc[m][n][j]);
                }
            }
    } else {
#pragma unroll
        for (int m = 0; m < MR; ++m)
#pragma unroll
            for (int n = 0; n < NR; ++n) {
                size_t col = bn + wc*(BN/2) + n*16 + cl;
#pragma unroll
                for (int j = 0; j < 4; ++j) {
                    size_t row = bm + wr*(BM/2) + m*16 + g*4 + j;
                    if constexpr (OMODE == 0)
                        ((float*)Cv)[row * N + col] = acc[m][n][j];
                    else if constexpr (OMODE == 1)
                        ((u16*)Cv)[row * N + col] = f2bf(acc[m][n][j]);
                    else
                        ((u16*)Cv)[col * M + row] = f2bf(acc[m][n][j]);
                }
            }
    }
}

// =====================================================================
// Vectorized transpose+cast: fp32 [K][N] -> bf16 [N][K]. 64x64 tiles,
// float4 loads, ushort4 stores, padded LDS (conflict-free column reads).
// =====================================================================
__device__ __forceinline__ void tc_body(
    const float* __restrict__ in, u16* __restrict__ out, int K, int N,
    int bk, int bn, int tid)
{
    __shared__ float tile[64][65];
    const int tx = tid & 15, ty = tid >> 4;
#pragma unroll
    for (int r0 = 0; r0 < 4; ++r0)
        *(float4*)&tile[ty + r0*16][tx*4] =
            *(const float4*)&in[(size_t)(bk + ty + r0*16) * N + bn + tx*4];
    __syncthreads();
#pragma unroll
    for (int r0 = 0; r0 < 4; ++r0) {
        const int nn = ty + r0*16;
        ushort4 o;
        o.x = f2bf(tile[tx*4+0][nn]);
        o.y = f2bf(tile[tx*4+1][nn]);
        o.z = f2bf(tile[tx*4+2][nn]);
        o.w = f2bf(tile[tx*4+3][nn]);
        *(ushort4*)&out[(size_t)(bn + nn) * K + bk + tx*4] = o;
    }
}

__global__ __launch_bounds__(256) void transpose_cast5v(
    const float* __restrict__ w0, u16* __restrict__ o0,
    const float* __restrict__ w1, u16* __restrict__ o1,
    const float* __restrict__ w2, u16* __restrict__ o2,
    const float* __restrict__ w3, u16* __restrict__ o3,
    const float* __restrict__ w4, u16* __restrict__ o4)
{
    const int z = blockIdx.z;
    const float* in; u16* out; int K, N;
    if      (z == 0) { in = w0; out = o0; K = 2048; N = 1536; }
    else if (z == 1) { in = w1; out = o1; K = 2048; N = 512;  }
    else if (z == 2) { in = w2; out = o2; K = 1536; N = 3072; }
    else if (z == 3) { in = w3; out = o3; K = 512;  N = 3072; }
    else             { in = w4; out = o4; K = 512;  N = 2048; }
    const int bn = blockIdx.x * 64, bk = blockIdx.y * 64;
    if (bn >= N || bk >= K) return;
    tc_body(in, out, K, N, bk, bn, threadIdx.x);
}

__global__ __launch_bounds__(256) void transpose_cast_v(
    const float* __restrict__ in, u16* __restrict__ out, int K, int N)
{
    tc_body(in, out, K, N, blockIdx.y * 64, blockIdx.x * 64, threadIdx.x);
}

__global__ __launch_bounds__(256) void cast_f32_bf16(
    const float* __restrict__ in, u16* __restrict__ out, long n)
{
    long i = ((long)blockIdx.x * 256 + threadIdx.x) * 4;
    if (i >= n) return;
    f32x4 v = *(const f32x4*)(in + i);
    ushort4 q;
    q.x = f2bf(v[0]); q.y = f2bf(v[1]); q.z = f2bf(v[2]); q.w = f2bf(v[3]);
    *(ushort4*)(out + i) = q;
}

// =====================================================================
// Fused double RMSNorm over bf16 buffers (in place).
// =====================================================================
__global__ __launch_bounds__(256) void rmsnorm2(
    u16* __restrict__ qb, const float* __restrict__ qw,
    u16* __restrict__ kvb, const float* __restrict__ kvw)
{
    const int r = blockIdx.x;
    u16* buf; const float* w; int N; float invN;
    if (r < 2048) { buf = qb + (size_t)r * 1536; w = qw; N = 1536; invN = 1.f/1536.f; }
    else { buf = kvb + (size_t)(r - 2048) * 512; w = kvw; N = 512; invN = 1.f/512.f; }
    const int t = threadIdx.x;

    float ss = 0.f;
    for (int i = t * 8; i < N; i += 2048) {
        s16x8 v = *(const s16x8*)&buf[i];
#pragma unroll
        for (int e = 0; e < 8; ++e) { float f = bf2f((u16)v[e]); ss += f * f; }
    }
#pragma unroll
    for (int off = 32; off > 0; off >>= 1) ss += __shfl_down(ss, off, 64);
    __shared__ float red[4];
    __shared__ float sinv;
    if ((t & 63) == 0) red[t >> 6] = ss;
    __syncthreads();
    if (t == 0) sinv = rsqrtf((red[0]+red[1]+red[2]+red[3]) * invN + 1e-5f);
    __syncthreads();
    const float si = sinv;
    for (int i = t * 8; i < N; i += 2048) {
        s16x8 v = *(const s16x8*)&buf[i];
        s16x8 o;
#pragma unroll
        for (int e = 0; e < 8; ++e)
            o[e] = (short)f2bf(bf2f((u16)v[e]) * w[i + e] * si);
        *(s16x8*)&buf[i] = o;
    }
}

// RoPE cos/sin table: [S][32]
__global__ __launch_bounds__(256) void rope_table_k(
    float* __restrict__ cost, float* __restrict__ sint)
{
    int idx = blockIdx.x * 256 + threadIdx.x;     // S*32
    int tp = idx >> 5, j = idx & 31;
    float invf = powf(100000.0f, -(float)j * (1.0f / 32.0f));
    float fr = (float)tp * invf;
    cost[idx] = cosf(fr);
    sint[idx] = sinf(fr);
}

// =====================================================================
// Attention (R7, unchanged): swapped QK^T + in-reg softmax + MFMA PV.
// K double-buffered in LDS; counted vmcnt; raw barriers. LDS 72KB.
// =====================================================================
__global__ __launch_bounds__(256) void attn_mfma(
    const u16* __restrict__ qg, const u16* __restrict__ kg,
    const u16* __restrict__ vtg, u16* __restrict__ og)
{
    __shared__ u16 Ks[2][64 * 192];    // 2x24KB, row 384B, swz (row&7)<<4
    __shared__ u16 VTs[128 * 64];      // 16KB, row 128B, swz (dv&7)<<4
    __shared__ u16 Ps[4][16 * 64];     // 8KB, per-wave, row 128B, swz (q&7)<<4

    const int t = threadIdx.x, lane = t & 63, wid = t >> 6;
    const int g = lane >> 4, cl = lane & 15;
    const int h = blockIdx.y;
    const int bx = blockIdx.x;
    const int qt = (bx & 1) ? (31 - (bx >> 1)) : (bx >> 1);  // causal balance
    const int qbase = qt * 64;
    const int wrow = wid * 16;

    s16x8 qv[6];
    {
        const u16* qrow = qg + (size_t)(qbase + wrow + cl) * QCOLS + h * 192;
#pragma unroll
        for (int s = 0; s < 6; ++s)
            qv[s] = *(const s16x8*)(qrow + s * 32 + g * 8);
    }

    float mreg = -1e30f, lreg = 0.f;   // running max/sum for q = cl
    f32x4 accO[8] = {};                // O[q=g*4+j][dv=nb*16+cl]
    char* pw = (char*)Ps[wid];

    const char* kh = (const char*)(kg + (size_t)h * 192);
    const char* vh = (const char*)(vtg + (size_t)(h * 128) * S_LEN);

    auto stageK = [&](int kt2, int buf) {
        const char* ksrc = kh + (size_t)(kt2 * 64) * (QCOLS * 2);
#pragma unroll
        for (int i = 0; i < 6; ++i) {
            int rnd = wid * 6 + i;
            int fb  = (rnd << 10) + (lane << 4);
            int row = fb / 384;
            int cb  = fb - row * 384;
            gload_lds16(ksrc + (size_t)row * (QCOLS * 2) + (cb ^ ((row & 7) << 4)),
                        (char*)Ks + buf * 24576 + (rnd << 10));
        }
    };
    auto stageV = [&](int kt2) {
        const char* vsrc = vh + (size_t)(kt2 * 64) * 2;
#pragma unroll
        for (int i = 0; i < 4; ++i) {
            int rnd = wid * 4 + i;
            int fb  = (rnd << 10) + (lane << 4);
            int dv  = fb >> 7;
            int cb  = fb & 127;
            gload_lds16(vsrc + (size_t)dv * (S_LEN * 2) + (cb ^ ((dv & 7) << 4)),
                        (char*)VTs + (rnd << 10));
        }
    };

    stageK(0, 0);
    asm volatile("s_waitcnt vmcnt(0)" ::: "memory");
    __builtin_amdgcn_s_barrier();

    int cur = 0;
    for (int kt = 0; kt <= qt; ++kt) {
        const int kbase = kt * 64;
        stageV(kt);                               // 4 gloads -> VTs
        if (kt < qt) stageK(kt + 1, cur ^ 1);     // 6 gloads -> Ks[cur^1]

        // ---- QK^T swapped (from resident Ks[cur]): kv=n*16+g*4+j, q=cl ----
        f32x4 accS[4] = {};
        const char* kbuf = (const char*)Ks + cur * 24576;
        __builtin_amdgcn_s_setprio(1);
#pragma unroll
        for (int n = 0; n < 4; ++n) {
            const int kvrow = n * 16 + cl;
            const char* krow = kbuf + kvrow * 384;
            const int sw = (kvrow & 7) << 4;
#pragma unroll
            for (int s = 0; s < 6; ++s) {
                s16x8 kv8 = *(const s16x8*)(krow + ((s * 64 + g * 16) ^ sw));
                accS[n] = __builtin_amdgcn_mfma_f32_16x16x32_bf16(
                    __builtin_bit_cast(bf16x8, kv8),
                    __builtin_bit_cast(bf16x8, qv[s]), accS[n], 0, 0, 0);
            }
        }
        __builtin_amdgcn_s_setprio(0);

        // ---- mask + scale + online softmax, in-register (q = cl) ----
        const int qrow_g = qbase + wrow + cl;
        float pm[4][4];
        float mx = -1e30f;
#pragma unroll
        for (int n = 0; n < 4; ++n)
#pragma unroll
            for (int j = 0; j < 4; ++j) {
                int kcol = kbase + n * 16 + g * 4 + j;
                float s = accS[n][j] * ATT_SCALE;
                s = (kcol <= qrow_g) ? s : -1e30f;
                pm[n][j] = s;
                mx = fmaxf(mx, s);
            }
        mx = fmaxf(mx, __shfl_xor(mx, 16, 64));
        mx = fmaxf(mx, __shfl_xor(mx, 32, 64));
        float mnew = fmaxf(mreg, mx);
        float c = __expf(mreg - mnew);
        float rs = 0.f;
#pragma unroll
        for (int n = 0; n < 4; ++n)
#pragma unroll
            for (int j = 0; j < 4; ++j) {
                float p = __expf(pm[n][j] - mnew);
                pm[n][j] = p;
                rs += p;
            }
        rs += __shfl_xor(rs, 16, 64);
        rs += __shfl_xor(rs, 32, 64);
        lreg = lreg * c + rs;
        mreg = mnew;

        // ---- P write: 4x ds_write_b64 (row q=cl) ----
#pragma unroll
        for (int n = 0; n < 4; ++n) {
            s16x4 pk;
#pragma unroll
            for (int j = 0; j < 4; ++j) pk[j] = (short)f2bf(pm[n][j]);
            int byte = (cl * 128 + n * 32 + g * 8) ^ ((cl & 7) << 4);
            *(s16x4*)(pw + byte) = pk;
        }

        // ---- B1: V landed for all waves; K(kt+1) stays in flight ----
        if (kt < qt) { asm volatile("s_waitcnt vmcnt(6)" ::: "memory"); }
        else         { asm volatile("s_waitcnt vmcnt(0)" ::: "memory"); }
        __builtin_amdgcn_sched_barrier(0);
        __builtin_amdgcn_s_barrier();

        // ---- rescale O (c broadcast from lane q=g*4+j) ----
        float cj[4];
#pragma unroll
        for (int j = 0; j < 4; ++j) cj[j] = __shfl(c, g * 4 + j, 64);
#pragma unroll
        for (int nb = 0; nb < 8; ++nb)
#pragma unroll
            for (int j = 0; j < 4; ++j) accO[nb][j] *= cj[j];

        // ---- PV via MFMA ----
        __builtin_amdgcn_s_setprio(1);
#pragma unroll
        for (int ks = 0; ks < 2; ++ks) {
            s16x8 pa = *(const s16x8*)(pw +
                ((cl * 128 + ks * 64 + g * 16) ^ ((cl & 7) << 4)));
#pragma unroll
            for (int nb = 0; nb < 8; ++nb) {
                s16x8 vb = *(const s16x8*)((const char*)VTs +
                    (((nb * 16 + cl) * 128 + ks * 64 + g * 16) ^ ((cl & 7) << 4)));
                accO[nb] = __builtin_amdgcn_mfma_f32_16x16x32_bf16(
                    __builtin_bit_cast(bf16x8, pa),
                    __builtin_bit_cast(bf16x8, vb), accO[nb], 0, 0, 0);
            }
        }
        __builtin_amdgcn_s_setprio(0);

        // ---- B0: K(kt+1) landed; all waves done with VTs ----
        asm volatile("s_waitcnt vmcnt(0)" ::: "memory");
        __builtin_amdgcn_sched_barrier(0);
        __builtin_amdgcn_s_barrier();
        cur ^= 1;
    }

    // ---- epilogue: O /= l (broadcast from lane q=g*4+j), store bf16 ----
    float li[4];
#pragma unroll
    for (int j = 0; j < 4; ++j) li[j] = 1.f / __shfl(lreg, g * 4 + j, 64);
#pragma unroll
    for (int j = 0; j < 4; ++j) {
        u16* orow = og + (size_t)(qbase + wrow + g * 4 + j) * VCOLS + h * 128;
#pragma unroll
        for (int nb = 0; nb < 8; ++nb)
            orow[nb * 16 + cl] = f2bf(accO[nb][j] * li[j]);
    }
}

// =====================================================================
// Host launcher
// =====================================================================
extern "C" void kernel_launch(void* const* d_in, const int* in_sizes, int n_in,
                              void* d_out, int out_size, void* d_ws, size_t ws_size,
                              hipStream_t stream)
{
    const float* x         = (const float*)d_in[0];
    const float* wq_down   = (const float*)d_in[1];
    const float* q_norm_w  = (const float*)d_in[2];
    const float* wq_up     = (const float*)d_in[3];
    const float* wkv_down  = (const float*)d_in[4];
    const float* kv_norm_w = (const float*)d_in[5];
    const float* wk_up     = (const float*)d_in[6];
    const float* wv_up     = (const float*)d_in[7];
    const float* wo        = (const float*)d_in[8];
    float* out = (float*)d_out;
    char* ws = (char*)d_ws;

    u16*  WQD_T  = (u16*)(ws + 0);            // 6,291,456 B  (contiguous with
    u16*  WKVD_T = (u16*)(ws + 6291456);      // 2,097,152    WKVD_T: fused N=2048)
    u16*  WKU_T  = (u16*)(ws + 8388608);      // 3,145,728  (contiguous with
    u16*  WVU_T  = (u16*)(ws + 11534336);     // 2,097,152   WVU_T: fused N=5120)
    u16*  WQU_T  = (u16*)(ws + 13631488);     // 9,437,184
    u16*  XBF    = (u16*)(ws + 23068672);     // 8,388,608
    u16*  VTBUF  = (u16*)(ws + 31457280);     // 8,388,608
    u16*  QLATB  = (u16*)(ws + 48234496);     // 6,291,456 (bf16, in-place norm)
    u16*  KVLATB = (u16*)(ws + 54525952);     // 2,097,152
    u16*  QBUF   = (u16*)(ws + 56623104);     // 12,582,912
    u16*  KBUF   = (u16*)(ws + 69206016);     // 12,582,912
    float* COST  = (float*)(ws + 81788928);   // 262,144
    float* SINT  = (float*)(ws + 82051072);   // 262,144
    // aliases over dead regions:
    u16*  WO_T   = (u16*)(ws + 0);            // over WQD_T+WKVD_T (dead after down-proj)
    u16*  ATTNO  = (u16*)(ws + 23068672);     // over XBF (dead after down-proj)

    // weight prep + x cast + rope table
    transpose_cast5v<<<dim3(48, 32, 5), 256, 0, stream>>>(
        wq_down, WQD_T, wkv_down, WKVD_T, wq_up, WQU_T, wk_up, WKU_T, wv_up, WVU_T);
    cast_f32_bf16<<<4096, 256, 0, stream>>>(x, XBF, (long)S_LEN * 2048);
    rope_table_k<<<256, 256, 0, stream>>>(COST, SINT);

    // fused down-projections (one GEMM, N=2048 over concat [WQD_T;WKVD_T])
    gemm_bf16<128,128,5><<<dim3(16, 16), 256, 0, stream>>>(
        XBF, WQD_T, QLATB, 2048, 2048, 2048, nullptr, nullptr, KVLATB);
    rmsnorm2<<<4096, 256, 0, stream>>>(QLATB, q_norm_w, KVLATB, kv_norm_w);
    transpose_cast_v<<<dim3(32, 32), 256, 0, stream>>>(wo, WO_T, 2048, 2048);

    // up-projections: q (rope fused); k+v fused in ONE gemm (N=5120)
    gemm_bf16<128,128,3><<<dim3(24, 16), 256, 0, stream>>>(
        QLATB,  WQU_T, QBUF, 2048, 3072, 1536, COST, SINT, nullptr);
    gemm_bf16<128,128,4><<<dim3(40, 16), 256, 0, stream>>>(
        KVLATB, WKU_T, KBUF, 2048, 5120, 512,  COST, SINT, VTBUF);

    // attention + output projection
    attn_mfma<<<dim3(32, 16), 256, 0, stream>>>(QBUF, KBUF, VTBUF, ATTNO);
    gemm_bf16<128,128,0><<<dim3(16, 16), 256, 0, stream>>>(
        ATTNO, WO_T, out, 2048, 2048, 2048, nullptr, nullptr, nullptr);
}